// Round 27
// baseline (189.232 us; speedup 1.0000x reference)
//
#include <hip/hip_runtime.h>

typedef unsigned short u16;
using bf16x8 = __attribute__((ext_vector_type(8))) __bf16;
using f32x4  = __attribute__((ext_vector_type(4))) float;

// SCALE * log2(e): softmax runs in exp2 domain
#define QSCALE 0.18033688011f

#define EXP2F(x) __builtin_amdgcn_exp2f(x)
#define SCHED_FENCE() __builtin_amdgcn_sched_barrier(0)

__device__ __forceinline__ u16 f2bf(float f) {
  union { float f; unsigned int u; } x; x.f = f;
  unsigned int r = x.u + 0x7FFFu + ((x.u >> 16) & 1u);
  return (u16)(r >> 16);
}

__device__ __forceinline__ bf16x8 ld8(const u16* p) {
  return *reinterpret_cast<const bf16x8*>(p);
}

__device__ __forceinline__ void gload16(const void* g, void* l) {
  __builtin_amdgcn_global_load_lds(
      (const __attribute__((address_space(1))) unsigned int*)g,
      (__attribute__((address_space(3))) unsigned int*)l, 16, 0, 0);
}

__device__ __forceinline__ void cast8(const float* __restrict__ src, u16* __restrict__ dst,
                                      size_t i8) {
  const float4 v0 = reinterpret_cast<const float4*>(src)[i8 * 2];
  const float4 v1 = reinterpret_cast<const float4*>(src)[i8 * 2 + 1];
  ushort4 o0, o1;
  o0.x = f2bf(v0.x); o0.y = f2bf(v0.y); o0.z = f2bf(v0.z); o0.w = f2bf(v0.w);
  o1.x = f2bf(v1.x); o1.y = f2bf(v1.y); o1.z = f2bf(v1.z); o1.w = f2bf(v1.w);
  uint4 o;
  o.x = (unsigned)o0.x | ((unsigned)o0.y << 16);
  o.y = (unsigned)o0.z | ((unsigned)o0.w << 16);
  o.z = (unsigned)o1.x | ((unsigned)o1.y << 16);
  o.w = (unsigned)o1.z | ((unsigned)o1.w << 16);
  reinterpret_cast<uint4*>(dst)[i8] = o;  // full 16B store per lane
}

// All 7 f32->bf16 casts in ONE launch. y<3: activations (n8=1M) at out+y*XN8*8;
// y>=3: weights (n8=128K) at out+(3*XN8+(y-3)*WN8)*8. Grid-stride.
__global__ void cast7_f32_to_bf16(const float* __restrict__ xq, const float* __restrict__ xk,
                                  const float* __restrict__ xv, const float* __restrict__ wq,
                                  const float* __restrict__ wk, const float* __restrict__ wv,
                                  const float* __restrict__ wo, u16* __restrict__ out,
                                  int xn8, int wn8) {
  const int y = blockIdx.y;
  const float* src = (y == 0) ? xq : (y == 1) ? xk : (y == 2) ? xv
                   : (y == 3) ? wq : (y == 4) ? wk : (y == 5) ? wv : wo;
  const size_t n8 = (y < 3) ? (size_t)xn8 : (size_t)wn8;
  u16* dst = out + ((y < 3) ? (size_t)y * xn8 : (size_t)3 * xn8 + (size_t)(y - 3) * wn8) * 8;
  const size_t stride = (size_t)gridDim.x * 256;
  for (size_t i = (size_t)blockIdx.x * 256 + threadIdx.x; i < n8; i += stride)
    cast8(src, dst, i);
}

// ---- BK=32 slab-staged bf16 GEMM core, DOUBLE-BUFFERED, 32KB LDS (4 blk/CU) ----
// Slab s=0..1 rows 64s+(t>>2), source chunk (t&3)^sig(t>>2), sig(r)=(r+(r>>2))&3
// => LDS(r,c)=global chunk c^sig(r); fragment reads c=flh^sig(row), sig(row)
// reduces to (fr+(fr>>2))&3 (2-way bank spread per 16-lane quarter = free).
// Per iter: drain -> barrier -> stage next tile into other buf -> 16 MFMA.
// k ascending (bit-exact canary).
#define GEMM32DB_BODY(A_, B_)                                                        \
  __shared__ alignas(16) u16 lds_a[2][128 * 32];                                     \
  __shared__ alignas(16) u16 lds_b[2][128 * 32];                                     \
  const int t = threadIdx.x;                                                         \
  const int w = t >> 6, lane = t & 63;                                               \
  const int wr = w >> 1, wc = w & 1;                                                 \
  f32x4 acc[4][4];                                                                   \
  _Pragma("unroll") for (int i = 0; i < 4; ++i)                                      \
    _Pragma("unroll") for (int j = 0; j < 4; ++j) acc[i][j] = {0.f, 0.f, 0.f, 0.f};  \
  const int r2 = t >> 2;                                                             \
  const int sg = (r2 + (r2 >> 2)) & 3;                                               \
  const int c2 = ((t & 3) ^ sg) * 8;                                                 \
  const u16* gaa = A_ + (row0 + r2) * 1024 + c2;                                     \
  const u16* gbb = B_ + (col0 + r2) * 1024 + c2;                                     \
  const int fr = lane & 15;                                                          \
  const int flh = lane >> 4;                                                         \
  const int fko = ((flh ^ ((fr + (fr >> 2)) & 3)) * 8);                              \
  _Pragma("unroll") for (int s = 0; s < 2; ++s) {                                    \
    gload16(gaa + (size_t)(64 * s) * 1024, &lds_a[0][s * 2048 + w * 512]);           \
    gload16(gbb + (size_t)(64 * s) * 1024, &lds_b[0][s * 2048 + w * 512]);           \
  }                                                                                  \
  for (int it = 0; it < 32; ++it) {                                                  \
    const int cur = it & 1;                                                          \
    asm volatile("s_waitcnt vmcnt(0)" ::: "memory");                                 \
    SCHED_FENCE();                                                                   \
    __syncthreads();                                                                 \
    SCHED_FENCE();                                                                   \
    if (it != 31) {                                                                  \
      const int nk = (it + 1) * 32;                                                  \
      _Pragma("unroll") for (int s = 0; s < 2; ++s) {                                \
        gload16(gaa + (size_t)(64 * s) * 1024 + nk, &lds_a[cur ^ 1][s * 2048 + w * 512]); \
        gload16(gbb + (size_t)(64 * s) * 1024 + nk, &lds_b[cur ^ 1][s * 2048 + w * 512]); \
      }                                                                              \
    }                                                                                \
    SCHED_FENCE();                                                                   \
    bf16x8 af[4], bfr[4];                                                            \
    _Pragma("unroll") for (int i = 0; i < 4; ++i)                                    \
      af[i] = ld8(&lds_a[cur][(wr * 64 + i * 16 + fr) * 32 + fko]);                  \
    _Pragma("unroll") for (int j = 0; j < 4; ++j)                                    \
      bfr[j] = ld8(&lds_b[cur][(wc * 64 + j * 16 + fr) * 32 + fko]);                 \
    _Pragma("unroll") for (int i = 0; i < 4; ++i)                                    \
      _Pragma("unroll") for (int j = 0; j < 4; ++j)                                  \
        acc[i][j] = __builtin_amdgcn_mfma_f32_16x16x32_bf16(af[i], bfr[j], acc[i][j], 0, 0, 0); \
  }                                                                                  \
  const int er = (lane >> 4) * 4, ec = lane & 15;

// ---- BK=64 slab-staged bf16 GEMM core, DOUBLE-BUFFERED (r25 proven, gemm_out) ----
#define GEMM64_BODY(A_, B_)                                                          \
  __shared__ alignas(16) u16 lds_a[2][128 * 64];                                     \
  __shared__ alignas(16) u16 lds_b[2][128 * 64];                                     \
  const int t = threadIdx.x;                                                         \
  const int w = t >> 6, lane = t & 63;                                               \
  const int wr = w >> 1, wc = w & 1;                                                 \
  f32x4 acc[4][4];                                                                   \
  _Pragma("unroll") for (int i = 0; i < 4; ++i)                                      \
    _Pragma("unroll") for (int j = 0; j < 4; ++j) acc[i][j] = {0.f, 0.f, 0.f, 0.f};  \
  const int b_r = t >> 3;                                                            \
  const int b_c = ((t & 7) ^ (b_r & 7)) * 8;                                         \
  const u16* gaa = A_ + (row0 + b_r) * 1024 + b_c;                                   \
  const u16* gbb = B_ + (col0 + b_r) * 1024 + b_c;                                   \
  const int fr = lane & 15;                                                          \
  const int flh = lane >> 4;                                                         \
  const int fx7 = fr & 7;                                                            \
  _Pragma("unroll") for (int s = 0; s < 4; ++s) {                                    \
    gload16(gaa + (size_t)(32 * s) * 1024, &lds_a[0][s * 2048 + w * 512]);           \
    gload16(gbb + (size_t)(32 * s) * 1024, &lds_b[0][s * 2048 + w * 512]);           \
  }                                                                                  \
  for (int it = 0; it < 16; ++it) {                                                  \
    const int cur = it & 1;                                                          \
    asm volatile("s_waitcnt vmcnt(0)" ::: "memory");                                 \
    SCHED_FENCE();                                                                   \
    __syncthreads();                                                                 \
    SCHED_FENCE();                                                                   \
    if (it != 15) {                                                                  \
      const int nk = (it + 1) * 64;                                                  \
      _Pragma("unroll") for (int s = 0; s < 4; ++s) {                                \
        gload16(gaa + (size_t)(32 * s) * 1024 + nk, &lds_a[cur ^ 1][s * 2048 + w * 512]); \
        gload16(gbb + (size_t)(32 * s) * 1024 + nk, &lds_b[cur ^ 1][s * 2048 + w * 512]); \
      }                                                                              \
    }                                                                                \
    SCHED_FENCE();                                                                   \
    _Pragma("unroll") for (int ks2 = 0; ks2 < 2; ++ks2) {                            \
      bf16x8 af[4], bfr[4];                                                          \
      const int gch = ks2 * 4 + flh;                                                 \
      _Pragma("unroll") for (int i = 0; i < 4; ++i)                                  \
        af[i] = ld8(&lds_a[cur][(wr * 64 + i * 16 + fr) * 64 + ((gch ^ fx7) * 8)]);  \
      _Pragma("unroll") for (int j = 0; j < 4; ++j)                                  \
        bfr[j] = ld8(&lds_b[cur][(wc * 64 + j * 16 + fr) * 64 + ((gch ^ fx7) * 8)]); \
      _Pragma("unroll") for (int i = 0; i < 4; ++i)                                  \
        _Pragma("unroll") for (int j = 0; j < 4; ++j)                                \
          acc[i][j] = __builtin_amdgcn_mfma_f32_16x16x32_bf16(af[i], bfr[j], acc[i][j], 0, 0, 0); \
    }                                                                                \
  }                                                                                  \
  const int er = (lane >> 4) * 4, ec = lane & 15;

// Q/K/V projections: bf16 A (pre-cast), dbuf BK=32 core (4 blk/CU). Grid 1536.
// z=0: Q * QSCALE. z=1: K per-row chunk XOR. z=2: V^T + PV key perm + XOR.
__global__ __launch_bounds__(256)
void gemm_qkv(const u16* __restrict__ Aall, const u16* __restrict__ Ball,
              u16* __restrict__ Call) {
  const int g = (blockIdx.x & 7) * 192 + (blockIdx.x >> 3);
  const int bx = g & 7, by = (g >> 3) & 63, z = g >> 9;
  const u16* A = Aall + (size_t)z * 8192 * 1024;
  const u16* B = Ball + (size_t)z * 1024 * 1024;
  u16* C = Call + (size_t)z * 8192 * 1024;
  const size_t row0 = (size_t)by * 128;
  const size_t col0 = (size_t)bx * 128;

  GEMM32DB_BODY(A, B)

#pragma unroll
  for (int i = 0; i < 4; ++i)
#pragma unroll
    for (int j = 0; j < 4; ++j) {
      const size_t row = row0 + wr * 64 + i * 16 + er;
      const size_t col = col0 + wc * 64 + j * 16 + ec;
      if (z == 0) {
#pragma unroll
        for (int r = 0; r < 4; ++r)
          C[(row + r) * 1024 + col] = f2bf(acc[i][j][r] * QSCALE);
      } else if (z == 1) {
        // K: swizzle dim chunk (8 dims = 16B) within head by key&7
#pragma unroll
        for (int r = 0; r < 4; ++r) {
          const size_t n = row + r;
          const size_t colswz = (col & ~(size_t)63) |
                                ((col & 63) ^ (((n & 7) << 3)));
          C[n * 1024 + colswz] = f2bf(acc[i][j][r]);
        }
      } else {
        // V^T per head: PV key permutation + key-chunk XOR by dim&7.
        ushort4 o4;
        o4.x = f2bf(acc[i][j][0]); o4.y = f2bf(acc[i][j][1]);
        o4.z = f2bf(acc[i][j][2]); o4.w = f2bf(acc[i][j][3]);
        const size_t nloc = row & 2047;
        const size_t d = col & 63;
        size_t pos = (nloc & ~(size_t)31) | (((nloc >> 2) & 3) << 3) |
                     (((nloc >> 4) & 1) << 2) | (nloc & 3);
        pos ^= (d & 7) << 3;
        const size_t idx = (((row >> 11) * 16 + (col >> 6)) * 64 + d) * 2048 + pos;
        *reinterpret_cast<ushort4*>(&C[idx]) = o4;
      }
    }
}

// Out-projection, dbuf BK=64 core (r25 proven): f32 out + bias. Grid 512, XCD swz.
__global__ __launch_bounds__(256)
void gemm_out(const u16* __restrict__ A, const u16* __restrict__ B,
              float* __restrict__ Cf, const float* __restrict__ bias) {
  const int g = (blockIdx.x & 7) * 64 + (blockIdx.x >> 3);
  const int bx = g & 7, by = g >> 3;
  const size_t row0 = (size_t)by * 128;
  const size_t col0 = (size_t)bx * 128;

  GEMM64_BODY(A, B)

#pragma unroll
  for (int i = 0; i < 4; ++i)
#pragma unroll
    for (int j = 0; j < 4; ++j) {
      const size_t row = row0 + wr * 64 + i * 16 + er;
      const size_t col = col0 + wc * 64 + j * 16 + ec;
#pragma unroll
      for (int r = 0; r < 4; ++r)
        Cf[(row + r) * 1024 + col] = acc[i][j][r] + bias[col];
    }
}

// Flash attention v9 (race-hardened, proven r13-r26 — unchanged).
__global__ __launch_bounds__(512)
void flash_attn(const u16* __restrict__ Q, const u16* __restrict__ Km,
                const u16* __restrict__ Vt, u16* __restrict__ O) {
  const int o_blk = (blockIdx.x & 7) * 64 + (blockIdx.x >> 3);
  const int qt = o_blk & 7, h = (o_blk >> 3) & 15, b = o_blk >> 7;
  const int t = threadIdx.x;
  const int w = t >> 6, lane = t & 63;
  const int l16 = lane & 15, lh = lane >> 4;

  __shared__ alignas(16) u16 kt_lds[2][64][64];
  __shared__ alignas(16) u16 vt_lds[2][64][64];

  const size_t base_qk = ((size_t)b * 2048) * 1024 + (size_t)h * 64;
  const size_t base_vt = ((size_t)(b * 16 + h)) * 64 * 2048;

  bf16x8 qf[2][2];
#pragma unroll
  for (int g = 0; g < 2; ++g) {
    const size_t qrow = (size_t)qt * 256 + (w * 2 + g) * 16 + l16;
    const u16* qp = Q + base_qk + qrow * 1024 + lh * 8;
    qf[g][0] = ld8(qp);
    qf[g][1] = ld8(qp + 32);
  }

  bf16x8 vones;
#pragma unroll
  for (int i = 0; i < 8; ++i) vones[i] = (__bf16)1.0f;

  f32x4 o_acc[2][4];
  f32x4 o_sum[2];
#pragma unroll
  for (int g = 0; g < 2; ++g) {
#pragma unroll
    for (int j = 0; j < 4; ++j) o_acc[g][j] = {0.f, 0.f, 0.f, 0.f};
    o_sum[g] = {0.f, 0.f, 0.f, 0.f};
  }

  const int srow = t >> 3;
  const int schk = (t & 7) * 8;
  const u16* kg = Km + base_qk + (size_t)srow * 1024 + schk;
  const u16* vg = Vt + base_vt + (size_t)srow * 2048 + schk;
  u16* kl0 = &kt_lds[0][0][0] + w * 512;
  u16* kl1 = &kt_lds[1][0][0] + w * 512;
  u16* vl0 = &vt_lds[0][0][0] + w * 512;
  u16* vl1 = &vt_lds[1][0][0] + w * 512;

  gload16(kg, kl0);
  gload16(vg, vl0);

  const int xo = (l16 & 7) << 3;

  for (int it = 0; it < 32; ++it) {
    const int cur = it & 1;
    asm volatile("s_waitcnt vmcnt(0)" ::: "memory");
    SCHED_FENCE();
    __syncthreads();
    SCHED_FENCE();

    if (it != 31) {
      const int nkv = (it + 1) * 64;
      gload16(kg + (size_t)nkv * 1024, cur ? kl0 : kl1);
      gload16(vg + nkv, cur ? vl0 : vl1);
    }
    SCHED_FENCE();

    f32x4 s[2][4];
#pragma unroll
    for (int g = 0; g < 2; ++g)
#pragma unroll
      for (int j = 0; j < 4; ++j) s[g][j] = {0.f, 0.f, 0.f, 0.f};
    __builtin_amdgcn_s_setprio(1);
#pragma unroll
    for (int j = 0; j < 4; ++j)
#pragma unroll
      for (int ks = 0; ks < 2; ++ks) {
        bf16x8 kf = ld8(&kt_lds[cur][j * 16 + l16][(ks * 32 + lh * 8) ^ xo]);
        s[0][j] = __builtin_amdgcn_mfma_f32_16x16x32_bf16(kf, qf[0][ks], s[0][j], 0, 0, 0);
        s[1][j] = __builtin_amdgcn_mfma_f32_16x16x32_bf16(kf, qf[1][ks], s[1][j], 0, 0, 0);
      }
    __builtin_amdgcn_s_setprio(0);

    bf16x8 pa[2][2];
#pragma unroll
    for (int g = 0; g < 2; ++g)
#pragma unroll
      for (int j = 0; j < 4; ++j)
#pragma unroll
        for (int r = 0; r < 4; ++r)
          s[g][j][r] = EXP2F(s[g][j][r]);
#pragma unroll
    for (int g = 0; g < 2; ++g)
#pragma unroll
      for (int c = 0; c < 2; ++c)
#pragma unroll
        for (int i = 0; i < 8; ++i)
          pa[g][c][i] = (__bf16)s[g][2 * c + (i >> 2)][i & 3];

    __builtin_amdgcn_s_setprio(1);
#pragma unroll
    for (int c = 0; c < 2; ++c) {
      o_sum[0] = __builtin_amdgcn_mfma_f32_16x16x32_bf16(pa[0][c], vones, o_sum[0], 0, 0, 0);
      o_sum[1] = __builtin_amdgcn_mfma_f32_16x16x32_bf16(pa[1][c], vones, o_sum[1], 0, 0, 0);
#pragma unroll
      for (int jd = 0; jd < 4; ++jd) {
        bf16x8 vf = ld8(&vt_lds[cur][jd * 16 + l16][(c * 32 + lh * 8) ^ xo]);
        o_acc[0][jd] = __builtin_amdgcn_mfma_f32_16x16x32_bf16(pa[0][c], vf, o_acc[0][jd], 0, 0, 0);
        o_acc[1][jd] = __builtin_amdgcn_mfma_f32_16x16x32_bf16(pa[1][c], vf, o_acc[1][jd], 0, 0, 0);
      }
    }
    __builtin_amdgcn_s_setprio(0);
  }

#pragma unroll
  for (int g = 0; g < 2; ++g) {
    float linv[4];
#pragma unroll
    for (int r = 0; r < 4; ++r) linv[r] = 1.0f / o_sum[g][r];
    const size_t orow0 = (size_t)b * 2048 + (size_t)qt * 256 + (w * 2 + g) * 16;
#pragma unroll
    for (int jd = 0; jd < 4; ++jd) {
      const int col = h * 64 + jd * 16 + l16;
#pragma unroll
      for (int r = 0; r < 4; ++r)
        O[(orow0 + lh * 4 + r) * 1024 + col] = f2bf(o_acc[g][jd][r] * linv[r]);
    }
  }
}

extern "C" void kernel_launch(void* const* d_in, const int* in_sizes, int n_in,
                              void* d_out, int out_size, void* d_ws, size_t ws_size,
                              hipStream_t stream) {
  const float* xq = (const float*)d_in[0];
  const float* xk = (const float*)d_in[1];
  const float* xv = (const float*)d_in[2];
  const float* Wq = (const float*)d_in[3];
  const float* Wk = (const float*)d_in[4];
  const float* Wv = (const float*)d_in[5];
  const float* Wo = (const float*)d_in[6];
  const float* bo = (const float*)d_in[7];
  float* out = (float*)d_out;

  const size_t X = (size_t)8192 * 1024;
  const size_t W = (size_t)1024 * 1024;

  u16* p = (u16*)d_ws;
  u16* x_bf  = p; p += 3 * X;          // xq | xk | xv (contiguous)
  u16* w_bf  = p; p += 4 * W;          // Wq | Wk | Wv | Wo (contiguous after x_bf)
  u16* qkv   = p; p += 3 * X;          // Q | K(swz) | V^T(swz)
  u16* attn_bf = x_bf;                  // x_bf dead after projections; reuse

  dim3 blk(256);
  cast7_f32_to_bf16<<<dim3(2048, 7), blk, 0, stream>>>(xq, xk, xv, Wq, Wk, Wv, Wo,
                                                       x_bf, (int)(X / 8), (int)(W / 8));

  gemm_qkv<<<dim3(1536), blk, 0, stream>>>(x_bf, w_bf, qkv);

  flash_attn<<<dim3(512), dim3(512), 0, stream>>>(qkv, qkv + X, qkv + 2 * X, attn_bf);

  gemm_out<<<dim3(512), blk, 0, stream>>>(attn_bf, w_bf + 3 * W, out, bo);
}

// Round 28
// 177.402 us; speedup vs baseline: 1.0667x; 1.0667x over previous
//
#include <hip/hip_runtime.h>

typedef unsigned short u16;
using bf16x8 = __attribute__((ext_vector_type(8))) __bf16;
using f32x4  = __attribute__((ext_vector_type(4))) float;

// SCALE * log2(e): softmax runs in exp2 domain
#define QSCALE 0.18033688011f

#define EXP2F(x) __builtin_amdgcn_exp2f(x)
#define SCHED_FENCE() __builtin_amdgcn_sched_barrier(0)

__device__ __forceinline__ u16 f2bf(float f) {
  union { float f; unsigned int u; } x; x.f = f;
  unsigned int r = x.u + 0x7FFFu + ((x.u >> 16) & 1u);
  return (u16)(r >> 16);
}

__device__ __forceinline__ bf16x8 ld8(const u16* p) {
  return *reinterpret_cast<const bf16x8*>(p);
}

__device__ __forceinline__ void gload16(const void* g, void* l) {
  __builtin_amdgcn_global_load_lds(
      (const __attribute__((address_space(1))) unsigned int*)g,
      (__attribute__((address_space(3))) unsigned int*)l, 16, 0, 0);
}

__device__ __forceinline__ void cast8(const float* __restrict__ src, u16* __restrict__ dst,
                                      size_t i8) {
  const float4 v0 = reinterpret_cast<const float4*>(src)[i8 * 2];
  const float4 v1 = reinterpret_cast<const float4*>(src)[i8 * 2 + 1];
  ushort4 o0, o1;
  o0.x = f2bf(v0.x); o0.y = f2bf(v0.y); o0.z = f2bf(v0.z); o0.w = f2bf(v0.w);
  o1.x = f2bf(v1.x); o1.y = f2bf(v1.y); o1.z = f2bf(v1.z); o1.w = f2bf(v1.w);
  uint4 o;
  o.x = (unsigned)o0.x | ((unsigned)o0.y << 16);
  o.y = (unsigned)o0.z | ((unsigned)o0.w << 16);
  o.z = (unsigned)o1.x | ((unsigned)o1.y << 16);
  o.w = (unsigned)o1.z | ((unsigned)o1.w << 16);
  reinterpret_cast<uint4*>(dst)[i8] = o;  // full 16B store per lane
}

// All 7 f32->bf16 casts in ONE launch. y<3: activations (n8=1M) at out+y*xn8*8;
// y>=3: weights (n8=128K) at out+(3*xn8+(y-3)*wn8)*8. Grid-stride.
__global__ void cast7_f32_to_bf16(const float* __restrict__ xq, const float* __restrict__ xk,
                                  const float* __restrict__ xv, const float* __restrict__ wq,
                                  const float* __restrict__ wk, const float* __restrict__ wv,
                                  const float* __restrict__ wo, u16* __restrict__ out,
                                  int xn8, int wn8) {
  const int y = blockIdx.y;
  const float* src = (y == 0) ? xq : (y == 1) ? xk : (y == 2) ? xv
                   : (y == 3) ? wq : (y == 4) ? wk : (y == 5) ? wv : wo;
  const size_t n8 = (y < 3) ? (size_t)xn8 : (size_t)wn8;
  u16* dst = out + ((y < 3) ? (size_t)y * xn8 : (size_t)3 * xn8 + (size_t)(y - 3) * wn8) * 8;
  const size_t stride = (size_t)gridDim.x * 256;
  for (size_t i = (size_t)blockIdx.x * 256 + threadIdx.x; i < n8; i += stride)
    cast8(src, dst, i);
}

// ---- BK=64 slab-staged bf16 GEMM core, DOUBLE-BUFFERED (r25/r26 proven) ----
// LDS 2x(16+16)=64KB, 2 blocks/CU, zero bank conflicts. Per iter: drain (loads
// issued one compute phase ago -> latency hidden) -> barrier -> stage next tile
// into other buf -> compute. Slab s=0..3 rows 32s+(t>>3), source chunk
// (t&7)^((t>>3)&7) => LDS(r,c)=global chunk c^(r&7); fragment reads c=g^(fr&7);
// two K=32 sub-passes k-ascending (bit-exact canary).
#define GEMM64_BODY(A_, B_)                                                          \
  __shared__ alignas(16) u16 lds_a[2][128 * 64];                                     \
  __shared__ alignas(16) u16 lds_b[2][128 * 64];                                     \
  const int t = threadIdx.x;                                                         \
  const int w = t >> 6, lane = t & 63;                                               \
  const int wr = w >> 1, wc = w & 1;                                                 \
  f32x4 acc[4][4];                                                                   \
  _Pragma("unroll") for (int i = 0; i < 4; ++i)                                      \
    _Pragma("unroll") for (int j = 0; j < 4; ++j) acc[i][j] = {0.f, 0.f, 0.f, 0.f};  \
  const int b_r = t >> 3;                                                            \
  const int b_c = ((t & 7) ^ (b_r & 7)) * 8;                                         \
  const u16* gaa = A_ + (row0 + b_r) * 1024 + b_c;                                   \
  const u16* gbb = B_ + (col0 + b_r) * 1024 + b_c;                                   \
  const int fr = lane & 15;                                                          \
  const int flh = lane >> 4;                                                         \
  const int fx7 = fr & 7;                                                            \
  _Pragma("unroll") for (int s = 0; s < 4; ++s) {                                    \
    gload16(gaa + (size_t)(32 * s) * 1024, &lds_a[0][s * 2048 + w * 512]);           \
    gload16(gbb + (size_t)(32 * s) * 1024, &lds_b[0][s * 2048 + w * 512]);           \
  }                                                                                  \
  for (int it = 0; it < 16; ++it) {                                                  \
    const int cur = it & 1;                                                          \
    asm volatile("s_waitcnt vmcnt(0)" ::: "memory");                                 \
    SCHED_FENCE();                                                                   \
    __syncthreads();                                                                 \
    SCHED_FENCE();                                                                   \
    if (it != 15) {                                                                  \
      const int nk = (it + 1) * 64;                                                  \
      _Pragma("unroll") for (int s = 0; s < 4; ++s) {                                \
        gload16(gaa + (size_t)(32 * s) * 1024 + nk, &lds_a[cur ^ 1][s * 2048 + w * 512]); \
        gload16(gbb + (size_t)(32 * s) * 1024 + nk, &lds_b[cur ^ 1][s * 2048 + w * 512]); \
      }                                                                              \
    }                                                                                \
    SCHED_FENCE();                                                                   \
    _Pragma("unroll") for (int ks2 = 0; ks2 < 2; ++ks2) {                            \
      bf16x8 af[4], bfr[4];                                                          \
      const int gch = ks2 * 4 + flh;                                                 \
      _Pragma("unroll") for (int i = 0; i < 4; ++i)                                  \
        af[i] = ld8(&lds_a[cur][(wr * 64 + i * 16 + fr) * 64 + ((gch ^ fx7) * 8)]);  \
      _Pragma("unroll") for (int j = 0; j < 4; ++j)                                  \
        bfr[j] = ld8(&lds_b[cur][(wc * 64 + j * 16 + fr) * 64 + ((gch ^ fx7) * 8)]); \
      _Pragma("unroll") for (int i = 0; i < 4; ++i)                                  \
        _Pragma("unroll") for (int j = 0; j < 4; ++j)                                \
          acc[i][j] = __builtin_amdgcn_mfma_f32_16x16x32_bf16(af[i], bfr[j], acc[i][j], 0, 0, 0); \
    }                                                                                \
  }                                                                                  \
  const int er = (lane >> 4) * 4, ec = lane & 15;

// Q/K/V projections: bf16 A (pre-cast), dbuf BK=64 core. Grid 1536 = 8x192.
// z=0: Q * QSCALE. z=1: K per-row chunk XOR. z=2: V^T + PV key perm + XOR.
__global__ __launch_bounds__(256)
void gemm_qkv(const u16* __restrict__ Aall, const u16* __restrict__ Ball,
              u16* __restrict__ Call) {
  const int g = (blockIdx.x & 7) * 192 + (blockIdx.x >> 3);
  const int bx = g & 7, by = (g >> 3) & 63, z = g >> 9;
  const u16* A = Aall + (size_t)z * 8192 * 1024;
  const u16* B = Ball + (size_t)z * 1024 * 1024;
  u16* C = Call + (size_t)z * 8192 * 1024;
  const size_t row0 = (size_t)by * 128;
  const size_t col0 = (size_t)bx * 128;

  GEMM64_BODY(A, B)

#pragma unroll
  for (int i = 0; i < 4; ++i)
#pragma unroll
    for (int j = 0; j < 4; ++j) {
      const size_t row = row0 + wr * 64 + i * 16 + er;
      const size_t col = col0 + wc * 64 + j * 16 + ec;
      if (z == 0) {
#pragma unroll
        for (int r = 0; r < 4; ++r)
          C[(row + r) * 1024 + col] = f2bf(acc[i][j][r] * QSCALE);
      } else if (z == 1) {
        // K: swizzle dim chunk (8 dims = 16B) within head by key&7
#pragma unroll
        for (int r = 0; r < 4; ++r) {
          const size_t n = row + r;
          const size_t colswz = (col & ~(size_t)63) |
                                ((col & 63) ^ (((n & 7) << 3)));
          C[n * 1024 + colswz] = f2bf(acc[i][j][r]);
        }
      } else {
        // V^T per head: PV key permutation + key-chunk XOR by dim&7.
        ushort4 o4;
        o4.x = f2bf(acc[i][j][0]); o4.y = f2bf(acc[i][j][1]);
        o4.z = f2bf(acc[i][j][2]); o4.w = f2bf(acc[i][j][3]);
        const size_t nloc = row & 2047;
        const size_t d = col & 63;
        size_t pos = (nloc & ~(size_t)31) | (((nloc >> 2) & 3) << 3) |
                     (((nloc >> 4) & 1) << 2) | (nloc & 3);
        pos ^= (d & 7) << 3;
        const size_t idx = (((row >> 11) * 16 + (col >> 6)) * 64 + d) * 2048 + pos;
        *reinterpret_cast<ushort4*>(&C[idx]) = o4;
      }
    }
}

// Out-projection, dbuf BK=64 core: f32 out + bias. Grid 512, XCD swizzle.
__global__ __launch_bounds__(256)
void gemm_out(const u16* __restrict__ A, const u16* __restrict__ B,
              float* __restrict__ Cf, const float* __restrict__ bias) {
  const int g = (blockIdx.x & 7) * 64 + (blockIdx.x >> 3);
  const int bx = g & 7, by = g >> 3;
  const size_t row0 = (size_t)by * 128;
  const size_t col0 = (size_t)bx * 128;

  GEMM64_BODY(A, B)

#pragma unroll
  for (int i = 0; i < 4; ++i)
#pragma unroll
    for (int j = 0; j < 4; ++j) {
      const size_t row = row0 + wr * 64 + i * 16 + er;
      const size_t col = col0 + wc * 64 + j * 16 + ec;
#pragma unroll
      for (int r = 0; r < 4; ++r)
        Cf[(row + r) * 1024 + col] = acc[i][j][r] + bias[col];
    }
}

// Flash attention v9 (race-hardened, proven r13-r27 — unchanged).
__global__ __launch_bounds__(512)
void flash_attn(const u16* __restrict__ Q, const u16* __restrict__ Km,
                const u16* __restrict__ Vt, u16* __restrict__ O) {
  const int o_blk = (blockIdx.x & 7) * 64 + (blockIdx.x >> 3);
  const int qt = o_blk & 7, h = (o_blk >> 3) & 15, b = o_blk >> 7;
  const int t = threadIdx.x;
  const int w = t >> 6, lane = t & 63;
  const int l16 = lane & 15, lh = lane >> 4;

  __shared__ alignas(16) u16 kt_lds[2][64][64];
  __shared__ alignas(16) u16 vt_lds[2][64][64];

  const size_t base_qk = ((size_t)b * 2048) * 1024 + (size_t)h * 64;
  const size_t base_vt = ((size_t)(b * 16 + h)) * 64 * 2048;

  bf16x8 qf[2][2];
#pragma unroll
  for (int g = 0; g < 2; ++g) {
    const size_t qrow = (size_t)qt * 256 + (w * 2 + g) * 16 + l16;
    const u16* qp = Q + base_qk + qrow * 1024 + lh * 8;
    qf[g][0] = ld8(qp);
    qf[g][1] = ld8(qp + 32);
  }

  bf16x8 vones;
#pragma unroll
  for (int i = 0; i < 8; ++i) vones[i] = (__bf16)1.0f;

  f32x4 o_acc[2][4];
  f32x4 o_sum[2];
#pragma unroll
  for (int g = 0; g < 2; ++g) {
#pragma unroll
    for (int j = 0; j < 4; ++j) o_acc[g][j] = {0.f, 0.f, 0.f, 0.f};
    o_sum[g] = {0.f, 0.f, 0.f, 0.f};
  }

  const int srow = t >> 3;
  const int schk = (t & 7) * 8;
  const u16* kg = Km + base_qk + (size_t)srow * 1024 + schk;
  const u16* vg = Vt + base_vt + (size_t)srow * 2048 + schk;
  u16* kl0 = &kt_lds[0][0][0] + w * 512;
  u16* kl1 = &kt_lds[1][0][0] + w * 512;
  u16* vl0 = &vt_lds[0][0][0] + w * 512;
  u16* vl1 = &vt_lds[1][0][0] + w * 512;

  gload16(kg, kl0);
  gload16(vg, vl0);

  const int xo = (l16 & 7) << 3;

  for (int it = 0; it < 32; ++it) {
    const int cur = it & 1;
    asm volatile("s_waitcnt vmcnt(0)" ::: "memory");
    SCHED_FENCE();
    __syncthreads();
    SCHED_FENCE();

    if (it != 31) {
      const int nkv = (it + 1) * 64;
      gload16(kg + (size_t)nkv * 1024, cur ? kl0 : kl1);
      gload16(vg + nkv, cur ? vl0 : vl1);
    }
    SCHED_FENCE();

    f32x4 s[2][4];
#pragma unroll
    for (int g = 0; g < 2; ++g)
#pragma unroll
      for (int j = 0; j < 4; ++j) s[g][j] = {0.f, 0.f, 0.f, 0.f};
    __builtin_amdgcn_s_setprio(1);
#pragma unroll
    for (int j = 0; j < 4; ++j)
#pragma unroll
      for (int ks = 0; ks < 2; ++ks) {
        bf16x8 kf = ld8(&kt_lds[cur][j * 16 + l16][(ks * 32 + lh * 8) ^ xo]);
        s[0][j] = __builtin_amdgcn_mfma_f32_16x16x32_bf16(kf, qf[0][ks], s[0][j], 0, 0, 0);
        s[1][j] = __builtin_amdgcn_mfma_f32_16x16x32_bf16(kf, qf[1][ks], s[1][j], 0, 0, 0);
      }
    __builtin_amdgcn_s_setprio(0);

    bf16x8 pa[2][2];
#pragma unroll
    for (int g = 0; g < 2; ++g)
#pragma unroll
      for (int j = 0; j < 4; ++j)
#pragma unroll
        for (int r = 0; r < 4; ++r)
          s[g][j][r] = EXP2F(s[g][j][r]);
#pragma unroll
    for (int g = 0; g < 2; ++g)
#pragma unroll
      for (int c = 0; c < 2; ++c)
#pragma unroll
        for (int i = 0; i < 8; ++i)
          pa[g][c][i] = (__bf16)s[g][2 * c + (i >> 2)][i & 3];

    __builtin_amdgcn_s_setprio(1);
#pragma unroll
    for (int c = 0; c < 2; ++c) {
      o_sum[0] = __builtin_amdgcn_mfma_f32_16x16x32_bf16(pa[0][c], vones, o_sum[0], 0, 0, 0);
      o_sum[1] = __builtin_amdgcn_mfma_f32_16x16x32_bf16(pa[1][c], vones, o_sum[1], 0, 0, 0);
#pragma unroll
      for (int jd = 0; jd < 4; ++jd) {
        bf16x8 vf = ld8(&vt_lds[cur][jd * 16 + l16][(c * 32 + lh * 8) ^ xo]);
        o_acc[0][jd] = __builtin_amdgcn_mfma_f32_16x16x32_bf16(pa[0][c], vf, o_acc[0][jd], 0, 0, 0);
        o_acc[1][jd] = __builtin_amdgcn_mfma_f32_16x16x32_bf16(pa[1][c], vf, o_acc[1][jd], 0, 0, 0);
      }
    }
    __builtin_amdgcn_s_setprio(0);
  }

#pragma unroll
  for (int g = 0; g < 2; ++g) {
    float linv[4];
#pragma unroll
    for (int r = 0; r < 4; ++r) linv[r] = 1.0f / o_sum[g][r];
    const size_t orow0 = (size_t)b * 2048 + (size_t)qt * 256 + (w * 2 + g) * 16;
#pragma unroll
    for (int jd = 0; jd < 4; ++jd) {
      const int col = h * 64 + jd * 16 + l16;
#pragma unroll
      for (int r = 0; r < 4; ++r)
        O[(orow0 + lh * 4 + r) * 1024 + col] = f2bf(o_acc[g][jd][r] * linv[r]);
    }
  }
}

extern "C" void kernel_launch(void* const* d_in, const int* in_sizes, int n_in,
                              void* d_out, int out_size, void* d_ws, size_t ws_size,
                              hipStream_t stream) {
  const float* xq = (const float*)d_in[0];
  const float* xk = (const float*)d_in[1];
  const float* xv = (const float*)d_in[2];
  const float* Wq = (const float*)d_in[3];
  const float* Wk = (const float*)d_in[4];
  const float* Wv = (const float*)d_in[5];
  const float* Wo = (const float*)d_in[6];
  const float* bo = (const float*)d_in[7];
  float* out = (float*)d_out;

  const size_t X = (size_t)8192 * 1024;
  const size_t W = (size_t)1024 * 1024;

  u16* p = (u16*)d_ws;
  u16* x_bf  = p; p += 3 * X;          // xq | xk | xv (contiguous)
  u16* w_bf  = p; p += 4 * W;          // Wq | Wk | Wv | Wo (contiguous after x_bf)
  u16* qkv   = p; p += 3 * X;          // Q | K(swz) | V^T(swz)
  u16* attn_bf = x_bf;                  // x_bf dead after projections; reuse

  dim3 blk(256);
  cast7_f32_to_bf16<<<dim3(2048, 7), blk, 0, stream>>>(xq, xk, xv, Wq, Wk, Wv, Wo,
                                                       x_bf, (int)(X / 8), (int)(W / 8));

  gemm_qkv<<<dim3(1536), blk, 0, stream>>>(x_bf, w_bf, qkv);

  flash_attn<<<dim3(512), dim3(512), 0, stream>>>(qkv, qkv + X, qkv + 2 * X, attn_bf);

  gemm_out<<<dim3(512), blk, 0, stream>>>(attn_bf, w_bf + 3 * W, out, bo);
}

// Round 29
// 175.675 us; speedup vs baseline: 1.0772x; 1.0098x over previous
//
#include <hip/hip_runtime.h>

typedef unsigned short u16;
using bf16x8 = __attribute__((ext_vector_type(8))) __bf16;
using f32x4  = __attribute__((ext_vector_type(4))) float;

// SCALE * log2(e): softmax runs in exp2 domain
#define QSCALE 0.18033688011f

#define EXP2F(x) __builtin_amdgcn_exp2f(x)
#define SCHED_FENCE() __builtin_amdgcn_sched_barrier(0)

__device__ __forceinline__ u16 f2bf(float f) {
  union { float f; unsigned int u; } x; x.f = f;
  unsigned int r = x.u + 0x7FFFu + ((x.u >> 16) & 1u);
  return (u16)(r >> 16);
}

__device__ __forceinline__ bf16x8 ld8(const u16* p) {
  return *reinterpret_cast<const bf16x8*>(p);
}

__device__ __forceinline__ void gload16(const void* g, void* l) {
  __builtin_amdgcn_global_load_lds(
      (const __attribute__((address_space(1))) unsigned int*)g,
      (__attribute__((address_space(3))) unsigned int*)l, 16, 0, 0);
}

__device__ __forceinline__ void cast8(const float* __restrict__ src, u16* __restrict__ dst,
                                      size_t i8) {
  const float4 v0 = reinterpret_cast<const float4*>(src)[i8 * 2];
  const float4 v1 = reinterpret_cast<const float4*>(src)[i8 * 2 + 1];
  ushort4 o0, o1;
  o0.x = f2bf(v0.x); o0.y = f2bf(v0.y); o0.z = f2bf(v0.z); o0.w = f2bf(v0.w);
  o1.x = f2bf(v1.x); o1.y = f2bf(v1.y); o1.z = f2bf(v1.z); o1.w = f2bf(v1.w);
  uint4 o;
  o.x = (unsigned)o0.x | ((unsigned)o0.y << 16);
  o.y = (unsigned)o0.z | ((unsigned)o0.w << 16);
  o.z = (unsigned)o1.x | ((unsigned)o1.y << 16);
  o.w = (unsigned)o1.z | ((unsigned)o1.w << 16);
  reinterpret_cast<uint4*>(dst)[i8] = o;  // full 16B store per lane
}

// Weights f32->bf16, 4 slices, grid-stride, 8 elems/thread/iter.
__global__ void cast4_f32_to_bf16(const float* __restrict__ a, const float* __restrict__ b,
                                  const float* __restrict__ c, const float* __restrict__ d,
                                  u16* __restrict__ out, int n8) {
  const int y = blockIdx.y;
  const float* src = (y == 0) ? a : (y == 1) ? b : (y == 2) ? c : d;
  u16* dst = out + (size_t)y * n8 * 8;
  const size_t stride = (size_t)gridDim.x * 256;
  for (size_t i = (size_t)blockIdx.x * 256 + threadIdx.x; i < (size_t)n8; i += stride)
    cast8(src, dst, i);
}

// Q/K/V projections, fused f32 cast, BK=32 DOUBLE-BUFFERED (r23 session-best,
// proven bit-exact): drain -> barrier -> stage next tile into other buf ->
// compute; HBM latency hidden under compute. LDS 48 KB (A f32 2x16KB, B 2x8KB).
//   A [128][32] f32: slab s=0..3 rows 32s+(t>>3), src chunk (t&7)^((t>>3)&7)
//     => LDS(r,c) = global chunk c^(r&7); read c = g^(fr&7).
//   B [128][32] u16: slab s=0..1 rows 64s+(t>>2), src chunk (t&3)^((t>>2)&3)
//     => LDS(r,c) = global chunk c^(r&3); read c = flh^(fr&3).
// k ascending (bit-exact canary).
__global__ __launch_bounds__(256)
void gemm_qkv(const float* __restrict__ xq, const float* __restrict__ xk,
              const float* __restrict__ xv, const u16* __restrict__ Ball,
              u16* __restrict__ Call) {
  const int g = (blockIdx.x & 7) * 192 + (blockIdx.x >> 3);
  const int bx = g & 7, by = (g >> 3) & 63, z = g >> 9;
  const float* A = (z == 0) ? xq : (z == 1) ? xk : xv;
  const u16* B = Ball + (size_t)z * 1024 * 1024;
  u16* C = Call + (size_t)z * 8192 * 1024;

  __shared__ alignas(16) float lds_af[2][128 * 32];  // 2 x 16 KB
  __shared__ alignas(16) u16 lds_b[2][128 * 32];     // 2 x 8 KB
  const int t = threadIdx.x;
  const int w = t >> 6, lane = t & 63;
  const int wr = w >> 1, wc = w & 1;
  const size_t row0 = (size_t)by * 128;
  const size_t col0 = (size_t)bx * 128;

  f32x4 acc[4][4];
#pragma unroll
  for (int i = 0; i < 4; ++i)
#pragma unroll
    for (int j = 0; j < 4; ++j) acc[i][j] = {0.f, 0.f, 0.f, 0.f};

  const int a_r = t >> 3;
  const int a_c = ((t & 7) ^ (a_r & 7)) * 4;
  const float* gaf = A + (row0 + a_r) * 1024 + a_c;
  const int b_r = t >> 2;
  const int b_c = ((t & 3) ^ (b_r & 3)) * 8;
  const u16* gbb = B + (col0 + b_r) * 1024 + b_c;

  const int fr = lane & 15;
  const int flh = lane >> 4;
  const int fx7 = fr & 7;
  const int fko = ((flh ^ (fr & 3)) * 8);

#define STAGEQ(tile, buf)                                                          \
  do {                                                                             \
    _Pragma("unroll") for (int s = 0; s < 4; ++s)                                  \
      gload16(gaf + (size_t)(32 * s) * 1024 + (tile) * 32,                         \
              &lds_af[buf][s * 1024 + w * 256]);                                   \
    _Pragma("unroll") for (int s = 0; s < 2; ++s)                                  \
      gload16(gbb + (size_t)(64 * s) * 1024 + (tile) * 32,                         \
              &lds_b[buf][s * 2048 + w * 512]);                                    \
  } while (0)

  STAGEQ(0, 0);

  for (int it = 0; it < 32; ++it) {
    const int cur = it & 1;
    asm volatile("s_waitcnt vmcnt(0)" ::: "memory");
    SCHED_FENCE();
    __syncthreads();
    SCHED_FENCE();

    if (it != 31) STAGEQ(it + 1, cur ^ 1);
    SCHED_FENCE();

    bf16x8 af[4], bfr[4];
#pragma unroll
    for (int i = 0; i < 4; ++i) {
      const int row = wr * 64 + i * 16 + fr;
      const int g0 = flh * 2;            // f32 chunk pair (8 chunks/row)
      f32x4 lo = *reinterpret_cast<const f32x4*>(&lds_af[cur][row * 32 + ((g0 ^ fx7) << 2)]);
      f32x4 hi = *reinterpret_cast<const f32x4*>(&lds_af[cur][row * 32 + (((g0 + 1) ^ fx7) << 2)]);
      af[i][0] = (__bf16)lo[0]; af[i][1] = (__bf16)lo[1];
      af[i][2] = (__bf16)lo[2]; af[i][3] = (__bf16)lo[3];
      af[i][4] = (__bf16)hi[0]; af[i][5] = (__bf16)hi[1];
      af[i][6] = (__bf16)hi[2]; af[i][7] = (__bf16)hi[3];
    }
#pragma unroll
    for (int j = 0; j < 4; ++j)
      bfr[j] = ld8(&lds_b[cur][(wc * 64 + j * 16 + fr) * 32 + fko]);
#pragma unroll
    for (int i = 0; i < 4; ++i)
#pragma unroll
      for (int j = 0; j < 4; ++j)
        acc[i][j] = __builtin_amdgcn_mfma_f32_16x16x32_bf16(af[i], bfr[j], acc[i][j], 0, 0, 0);
  }
#undef STAGEQ

  const int er = (lane >> 4) * 4, ec = lane & 15;
#pragma unroll
  for (int i = 0; i < 4; ++i)
#pragma unroll
    for (int j = 0; j < 4; ++j) {
      const size_t row = row0 + wr * 64 + i * 16 + er;
      const size_t col = col0 + wc * 64 + j * 16 + ec;
      if (z == 0) {
#pragma unroll
        for (int r = 0; r < 4; ++r)
          C[(row + r) * 1024 + col] = f2bf(acc[i][j][r] * QSCALE);
      } else if (z == 1) {
        // K: swizzle dim chunk (8 dims = 16B) within head by key&7
#pragma unroll
        for (int r = 0; r < 4; ++r) {
          const size_t n = row + r;
          const size_t colswz = (col & ~(size_t)63) |
                                ((col & 63) ^ (((n & 7) << 3)));
          C[n * 1024 + colswz] = f2bf(acc[i][j][r]);
        }
      } else {
        // V^T per head: PV key permutation + key-chunk XOR by dim&7.
        ushort4 o4;
        o4.x = f2bf(acc[i][j][0]); o4.y = f2bf(acc[i][j][1]);
        o4.z = f2bf(acc[i][j][2]); o4.w = f2bf(acc[i][j][3]);
        const size_t nloc = row & 2047;
        const size_t d = col & 63;
        size_t pos = (nloc & ~(size_t)31) | (((nloc >> 2) & 3) << 3) |
                     (((nloc >> 4) & 1) << 2) | (nloc & 3);
        pos ^= (d & 7) << 3;
        const size_t idx = (((row >> 11) * 16 + (col >> 6)) * 64 + d) * 2048 + pos;
        *reinterpret_cast<ushort4*>(&C[idx]) = o4;
      }
    }
}

// Out-projection, BK=64 slab-staged DOUBLE-BUFFERED (r25/r28 proven): both
// operands bf16, LDS 64 KB; slab s=0..3 rows 32s+(t>>3), source chunk
// (t&7)^((t>>3)&7); fragment reads c=g^(fr&7); two K=32 sub-passes k-ascending.
// f32 out + bias. Grid 512, XCD swizzle.
__global__ __launch_bounds__(256)
void gemm_out(const u16* __restrict__ A, const u16* __restrict__ B,
              float* __restrict__ Cf, const float* __restrict__ bias) {
  const int g = (blockIdx.x & 7) * 64 + (blockIdx.x >> 3);
  const int bx = g & 7, by = g >> 3;
  const size_t row0 = (size_t)by * 128;
  const size_t col0 = (size_t)bx * 128;

  __shared__ alignas(16) u16 lds_a[2][128 * 64];
  __shared__ alignas(16) u16 lds_b[2][128 * 64];
  const int t = threadIdx.x;
  const int w = t >> 6, lane = t & 63;
  const int wr = w >> 1, wc = w & 1;
  f32x4 acc[4][4];
#pragma unroll
  for (int i = 0; i < 4; ++i)
#pragma unroll
    for (int j = 0; j < 4; ++j) acc[i][j] = {0.f, 0.f, 0.f, 0.f};
  const int b_r = t >> 3;
  const int b_c = ((t & 7) ^ (b_r & 7)) * 8;
  const u16* gaa = A + (row0 + b_r) * 1024 + b_c;
  const u16* gbb = B + (col0 + b_r) * 1024 + b_c;
  const int fr = lane & 15;
  const int flh = lane >> 4;
  const int fx7 = fr & 7;
#pragma unroll
  for (int s = 0; s < 4; ++s) {
    gload16(gaa + (size_t)(32 * s) * 1024, &lds_a[0][s * 2048 + w * 512]);
    gload16(gbb + (size_t)(32 * s) * 1024, &lds_b[0][s * 2048 + w * 512]);
  }
  for (int it = 0; it < 16; ++it) {
    const int cur = it & 1;
    asm volatile("s_waitcnt vmcnt(0)" ::: "memory");
    SCHED_FENCE();
    __syncthreads();
    SCHED_FENCE();
    if (it != 15) {
      const int nk = (it + 1) * 64;
#pragma unroll
      for (int s = 0; s < 4; ++s) {
        gload16(gaa + (size_t)(32 * s) * 1024 + nk, &lds_a[cur ^ 1][s * 2048 + w * 512]);
        gload16(gbb + (size_t)(32 * s) * 1024 + nk, &lds_b[cur ^ 1][s * 2048 + w * 512]);
      }
    }
    SCHED_FENCE();
#pragma unroll
    for (int ks2 = 0; ks2 < 2; ++ks2) {
      bf16x8 af[4], bfr[4];
      const int gch = ks2 * 4 + flh;
#pragma unroll
      for (int i = 0; i < 4; ++i)
        af[i] = ld8(&lds_a[cur][(wr * 64 + i * 16 + fr) * 64 + ((gch ^ fx7) * 8)]);
#pragma unroll
      for (int j = 0; j < 4; ++j)
        bfr[j] = ld8(&lds_b[cur][(wc * 64 + j * 16 + fr) * 64 + ((gch ^ fx7) * 8)]);
#pragma unroll
      for (int i = 0; i < 4; ++i)
#pragma unroll
        for (int j = 0; j < 4; ++j)
          acc[i][j] = __builtin_amdgcn_mfma_f32_16x16x32_bf16(af[i], bfr[j], acc[i][j], 0, 0, 0);
    }
  }
  const int er = (lane >> 4) * 4, ec = lane & 15;
#pragma unroll
  for (int i = 0; i < 4; ++i)
#pragma unroll
    for (int j = 0; j < 4; ++j) {
      const size_t row = row0 + wr * 64 + i * 16 + er;
      const size_t col = col0 + wc * 64 + j * 16 + ec;
#pragma unroll
      for (int r = 0; r < 4; ++r)
        Cf[(row + r) * 1024 + col] = acc[i][j][r] + bias[col];
    }
}

// Flash attention v9 (race-hardened, proven r13-r28 — unchanged).
__global__ __launch_bounds__(512)
void flash_attn(const u16* __restrict__ Q, const u16* __restrict__ Km,
                const u16* __restrict__ Vt, u16* __restrict__ O) {
  const int o_blk = (blockIdx.x & 7) * 64 + (blockIdx.x >> 3);
  const int qt = o_blk & 7, h = (o_blk >> 3) & 15, b = o_blk >> 7;
  const int t = threadIdx.x;
  const int w = t >> 6, lane = t & 63;
  const int l16 = lane & 15, lh = lane >> 4;

  __shared__ alignas(16) u16 kt_lds[2][64][64];
  __shared__ alignas(16) u16 vt_lds[2][64][64];

  const size_t base_qk = ((size_t)b * 2048) * 1024 + (size_t)h * 64;
  const size_t base_vt = ((size_t)(b * 16 + h)) * 64 * 2048;

  bf16x8 qf[2][2];
#pragma unroll
  for (int g = 0; g < 2; ++g) {
    const size_t qrow = (size_t)qt * 256 + (w * 2 + g) * 16 + l16;
    const u16* qp = Q + base_qk + qrow * 1024 + lh * 8;
    qf[g][0] = ld8(qp);
    qf[g][1] = ld8(qp + 32);
  }

  bf16x8 vones;
#pragma unroll
  for (int i = 0; i < 8; ++i) vones[i] = (__bf16)1.0f;

  f32x4 o_acc[2][4];
  f32x4 o_sum[2];
#pragma unroll
  for (int g = 0; g < 2; ++g) {
#pragma unroll
    for (int j = 0; j < 4; ++j) o_acc[g][j] = {0.f, 0.f, 0.f, 0.f};
    o_sum[g] = {0.f, 0.f, 0.f, 0.f};
  }

  const int srow = t >> 3;
  const int schk = (t & 7) * 8;
  const u16* kg = Km + base_qk + (size_t)srow * 1024 + schk;
  const u16* vg = Vt + base_vt + (size_t)srow * 2048 + schk;
  u16* kl0 = &kt_lds[0][0][0] + w * 512;
  u16* kl1 = &kt_lds[1][0][0] + w * 512;
  u16* vl0 = &vt_lds[0][0][0] + w * 512;
  u16* vl1 = &vt_lds[1][0][0] + w * 512;

  gload16(kg, kl0);
  gload16(vg, vl0);

  const int xo = (l16 & 7) << 3;

  for (int it = 0; it < 32; ++it) {
    const int cur = it & 1;
    asm volatile("s_waitcnt vmcnt(0)" ::: "memory");
    SCHED_FENCE();
    __syncthreads();
    SCHED_FENCE();

    if (it != 31) {
      const int nkv = (it + 1) * 64;
      gload16(kg + (size_t)nkv * 1024, cur ? kl0 : kl1);
      gload16(vg + nkv, cur ? vl0 : vl1);
    }
    SCHED_FENCE();

    f32x4 s[2][4];
#pragma unroll
    for (int g = 0; g < 2; ++g)
#pragma unroll
      for (int j = 0; j < 4; ++j) s[g][j] = {0.f, 0.f, 0.f, 0.f};
    __builtin_amdgcn_s_setprio(1);
#pragma unroll
    for (int j = 0; j < 4; ++j)
#pragma unroll
      for (int ks = 0; ks < 2; ++ks) {
        bf16x8 kf = ld8(&kt_lds[cur][j * 16 + l16][(ks * 32 + lh * 8) ^ xo]);
        s[0][j] = __builtin_amdgcn_mfma_f32_16x16x32_bf16(kf, qf[0][ks], s[0][j], 0, 0, 0);
        s[1][j] = __builtin_amdgcn_mfma_f32_16x16x32_bf16(kf, qf[1][ks], s[1][j], 0, 0, 0);
      }
    __builtin_amdgcn_s_setprio(0);

    bf16x8 pa[2][2];
#pragma unroll
    for (int g = 0; g < 2; ++g)
#pragma unroll
      for (int j = 0; j < 4; ++j)
#pragma unroll
        for (int r = 0; r < 4; ++r)
          s[g][j][r] = EXP2F(s[g][j][r]);
#pragma unroll
    for (int g = 0; g < 2; ++g)
#pragma unroll
      for (int c = 0; c < 2; ++c)
#pragma unroll
        for (int i = 0; i < 8; ++i)
          pa[g][c][i] = (__bf16)s[g][2 * c + (i >> 2)][i & 3];

    __builtin_amdgcn_s_setprio(1);
#pragma unroll
    for (int c = 0; c < 2; ++c) {
      o_sum[0] = __builtin_amdgcn_mfma_f32_16x16x32_bf16(pa[0][c], vones, o_sum[0], 0, 0, 0);
      o_sum[1] = __builtin_amdgcn_mfma_f32_16x16x32_bf16(pa[1][c], vones, o_sum[1], 0, 0, 0);
#pragma unroll
      for (int jd = 0; jd < 4; ++jd) {
        bf16x8 vf = ld8(&vt_lds[cur][jd * 16 + l16][(c * 32 + lh * 8) ^ xo]);
        o_acc[0][jd] = __builtin_amdgcn_mfma_f32_16x16x32_bf16(pa[0][c], vf, o_acc[0][jd], 0, 0, 0);
        o_acc[1][jd] = __builtin_amdgcn_mfma_f32_16x16x32_bf16(pa[1][c], vf, o_acc[1][jd], 0, 0, 0);
      }
    }
    __builtin_amdgcn_s_setprio(0);
  }

#pragma unroll
  for (int g = 0; g < 2; ++g) {
    float linv[4];
#pragma unroll
    for (int r = 0; r < 4; ++r) linv[r] = 1.0f / o_sum[g][r];
    const size_t orow0 = (size_t)b * 2048 + (size_t)qt * 256 + (w * 2 + g) * 16;
#pragma unroll
    for (int jd = 0; jd < 4; ++jd) {
      const int col = h * 64 + jd * 16 + l16;
#pragma unroll
      for (int r = 0; r < 4; ++r)
        O[(orow0 + lh * 4 + r) * 1024 + col] = f2bf(o_acc[g][jd][r] * linv[r]);
    }
  }
}

extern "C" void kernel_launch(void* const* d_in, const int* in_sizes, int n_in,
                              void* d_out, int out_size, void* d_ws, size_t ws_size,
                              hipStream_t stream) {
  const float* xq = (const float*)d_in[0];
  const float* xk = (const float*)d_in[1];
  const float* xv = (const float*)d_in[2];
  const float* Wq = (const float*)d_in[3];
  const float* Wk = (const float*)d_in[4];
  const float* Wv = (const float*)d_in[5];
  const float* Wo = (const float*)d_in[6];
  const float* bo = (const float*)d_in[7];
  float* out = (float*)d_out;

  const size_t X = (size_t)8192 * 1024;
  const size_t W = (size_t)1024 * 1024;

  u16* p = (u16*)d_ws;
  u16* attn_bf = p; p += X;            // attention output (bf16)
  u16* w_bf  = p; p += 4 * W;          // Wq | Wk | Wv | Wo
  u16* qkv   = p; p += 3 * X;          // Q | K(swz) | V^T(swz)

  dim3 blk(256);
  cast4_f32_to_bf16<<<dim3(512, 4), blk, 0, stream>>>(Wq, Wk, Wv, Wo, w_bf, (int)(W / 8));

  gemm_qkv<<<dim3(1536), blk, 0, stream>>>(xq, xk, xv, w_bf, qkv);

  flash_attn<<<dim3(512), dim3(512), 0, stream>>>(qkv, qkv + X, qkv + 2 * X, attn_bf);

  gemm_out<<<dim3(512), blk, 0, stream>>>(attn_bf, w_bf + 3 * W, out, bo);
}